// Round 17
// baseline (313.499 us; speedup 1.0000x reference)
//
#include <hip/hip_runtime.h>
#include <math.h>

#define NWTOK 343
#define NTOK 117649
#define QSCALE 0.510069734f   // (1/sqrt(8)) * log2(e)
#define LOG2E 1.4426950408889634f
#define QPLANE 1372   // u32 per (window,head) plane of f16 rows
#define OPLANE 2744   // f32 per (window,head) plane of o
#define NPAD 352
#define NTILE 22
#define NBIAS_BLK 2904        // 6*22*22 bias tiles
#define NK0_TILE 7546         // 343*22 token tiles

typedef unsigned int u32;
typedef __fp16 h2 __attribute__((ext_vector_type(2)));
typedef __fp16 h4 __attribute__((ext_vector_type(4)));
typedef float f32x4 __attribute__((ext_vector_type(4)));

__device__ __forceinline__ u32 packh2(float a, float b) {
    h2 h = __builtin_amdgcn_cvt_pkrtz(a, b);
    return __builtin_bit_cast(u32, h);
}
__device__ __forceinline__ h4 packh4(float a, float b, float c, float d) {
    return __builtin_bit_cast(h4, make_uint2(packh2(a, b), packh2(c, d)));
}
__device__ __forceinline__ float fast_exp2(float x) {
#if __has_builtin(__builtin_amdgcn_exp2f)
    return __builtin_amdgcn_exp2f(x);
#else
    return exp2f(x);
#endif
}

// Inline exact-GELU via Abramowitz-Stegun 7.1.26 erf (max abs err 1.5e-7).
__device__ __forceinline__ float gelu_exact(float x) {
    const float z = x * 0.70710678118654752f;
    const float az = fabsf(z);
    const float t = __builtin_amdgcn_rcpf(fmaf(0.3275911f, az, 1.0f));
    float y = fmaf(t, 1.061405429f, -1.453152027f);
    y = fmaf(t, y, 1.421413741f);
    y = fmaf(t, y, -0.284496736f);
    y = fmaf(t, y, 0.254829592f);
    y *= t;
    const float one_m_erf = y * __expf(-az * az);
    const float erf_az = 1.0f - one_m_erf;
    const float erf_z = (z < 0.f) ? -erf_az : erf_az;
    return 0.5f * x * (1.0f + erf_z);
}

// ---- K0 fused: blocks [0,2904) expand bias tiles; blocks >= 2904 do
// patch-embed + LN + LN1 + QKV(block 0) in the MFMA tile structure. ----
__global__ __launch_bounds__(256, 4) void k0_fused(
    const float* __restrict__ x,
    const float* __restrict__ pe_w,
    const float* __restrict__ pe_bias,
    const float* __restrict__ pe_g,
    const float* __restrict__ pe_b,
    const float* __restrict__ n1_g,
    const float* __restrict__ n1_b,
    const float* __restrict__ qkv_w,
    const float* __restrict__ rpb,     // (3, 2197, 2)
    float* __restrict__ xe,
    u32* __restrict__ qg,
    u32* __restrict__ kg,
    u32* __restrict__ vg,
    __fp16* __restrict__ bexp16)
{
    const int tid = threadIdx.x;

    if (blockIdx.x < NBIAS_BLK) {
        const int tile = blockIdx.x;
        const int kt = tile % NTILE;
        const int rest = tile / NTILE;
        const int qt = rest % NTILE;
        const int bh = rest / NTILE;
        const int blk = bh >> 1, h = bh & 1;
        const int n = tid >> 4, g = tid & 15;
        const int i = qt * 16 + n, j = kt * 16 + g;
        float val;
        if (j >= NWTOK) {
            val = -60.f;
        } else if (i >= NWTOK) {
            val = 0.f;
        } else {
            const int iz = i / 49, ir = i - iz * 49, iy = ir / 7, ix = ir - iy * 7;
            const int jz = j / 49, jr = j - jz * 49, jy = jr / 7, jx = jr - jy * 7;
            const int idx = (iz - jz + 6) * 169 + (iy - jy + 6) * 13 + (ix - jx + 6);
            val = rpb[((size_t)blk * 2197 + idx) * 2 + h] * LOG2E;
        }
        bexp16[(size_t)tile * 256 + tid] = (__fp16)val;
        return;
    }

    __shared__ float pw_s[128];
    __shared__ u32 qkvh[384];
    __shared__ float pb_s[16], g_s[16], b_s[16], n1g_s[16], n1b_s[16];

    if (tid < 128) pw_s[tid] = pe_w[tid];
    for (int i = tid; i < 384; i += 256) {
        const float2 a = ((const float2*)qkv_w)[i];
        qkvh[i] = packh2(a.x, a.y);
    }
    if (tid < 16) {
        pb_s[tid] = pe_bias[tid]; g_s[tid] = pe_g[tid]; b_s[tid] = pe_b[tid];
        n1g_s[tid] = n1_g[tid]; n1b_s[tid] = n1_b[tid];
    }
    __syncthreads();

    const int wave_id = (blockIdx.x - NBIAS_BLK) * 4 + (tid >> 6);
    if (wave_id >= NK0_TILE) return;
    const int w = wave_id / NTILE;
    const int qt = wave_id - w * NTILE;

    const int lane = tid & 63;
    const int tcol = lane & 15;
    const int g4 = (lane >> 4) * 4;
    const int tok = qt * 16 + tcol;
    const bool valid = (tok < NWTOK);
    const int tokc = valid ? tok : (NWTOK - 1);

    const int wd = w / 49, wr = w - wd * 49, wh = wr / 7, ww = wr - wh * 7;
    const int tz = tokc / 49, tr = tokc - tz * 49, ty = tr / 7, tx = tr - ty * 7;
    const int z = wd * 7 + tz, y = wh * 7 + ty, xx = ww * 7 + tx;
    const float* bp = x + ((size_t)(2 * z) * 98 + (2 * y)) * 98 + 2 * xx;
    float in[8];
    in[0] = bp[0];    in[1] = bp[1];
    in[2] = bp[98];   in[3] = bp[99];
    in[4] = bp[9604]; in[5] = bp[9605];
    in[6] = bp[9702]; in[7] = bp[9703];

    float c4[4];
    #pragma unroll
    for (int i = 0; i < 4; ++i) {
        const int ch = g4 + i;
        const float4 w0 = *(const float4*)(pw_s + ch * 8);
        const float4 w1 = *(const float4*)(pw_s + ch * 8 + 4);
        float a = pb_s[ch];
        a = fmaf(in[0], w0.x, a); a = fmaf(in[1], w0.y, a);
        a = fmaf(in[2], w0.z, a); a = fmaf(in[3], w0.w, a);
        a = fmaf(in[4], w1.x, a); a = fmaf(in[5], w1.y, a);
        a = fmaf(in[6], w1.z, a); a = fmaf(in[7], w1.w, a);
        c4[i] = a;
    }

    float s = (c4[0] + c4[1]) + (c4[2] + c4[3]);
    s += __shfl_xor(s, 16); s += __shfl_xor(s, 32);
    float mu = s * 0.0625f;
    float v0 = c4[0] - mu, v1 = c4[1] - mu, v2 = c4[2] - mu, v3 = c4[3] - mu;
    float vv = fmaf(v0, v0, fmaf(v1, v1, fmaf(v2, v2, v3 * v3)));
    vv += __shfl_xor(vv, 16); vv += __shfl_xor(vv, 32);
    float rs = rsqrtf(vv * 0.0625f + 1e-5f);
    const float4 gg = *(const float4*)(g_s + g4);
    const float4 bb = *(const float4*)(b_s + g4);
    const float o0 = v0 * rs * gg.x + bb.x;
    const float o1 = v1 * rs * gg.y + bb.y;
    const float o2 = v2 * rs * gg.z + bb.z;
    const float o3 = v3 * rs * gg.w + bb.w;

    if (valid)
        *(float4*)(xe + (size_t)(w * NWTOK + tok) * 16 + g4) = make_float4(o0, o1, o2, o3);

    s = (o0 + o1) + (o2 + o3);
    s += __shfl_xor(s, 16); s += __shfl_xor(s, 32);
    mu = s * 0.0625f;
    v0 = o0 - mu; v1 = o1 - mu; v2 = o2 - mu; v3 = o3 - mu;
    vv = fmaf(v0, v0, fmaf(v1, v1, fmaf(v2, v2, v3 * v3)));
    vv += __shfl_xor(vv, 16); vv += __shfl_xor(vv, 32);
    rs = rsqrtf(vv * 0.0625f + 1e-5f);
    const float4 g1 = *(const float4*)(n1g_s + g4);
    const float4 b1 = *(const float4*)(n1b_s + g4);
    const h4 yB = packh4(v0 * rs * g1.x + b1.x, v1 * rs * g1.y + b1.y,
                         v2 * rs * g1.z + b1.z, v3 * rs * g1.w + b1.w);

    const f32x4 zero = {0.f, 0.f, 0.f, 0.f};
    const int head = g4 >> 3;
    const int uoff = (g4 & 7) >> 1;
    const size_t qpl = (size_t)(w * 2 + head) * QPLANE + tok * 4 + uoff;
    #pragma unroll
    for (int m = 0; m < 3; ++m) {
        const uint2 aw = *(const uint2*)(qkvh + (m * 16 + tcol) * 8 + (g4 >> 1));
        f32x4 d = __builtin_amdgcn_mfma_f32_16x16x16f16(
            __builtin_bit_cast(h4, aw), yB, zero, 0, 0, 0);
        const float sc = (m == 0) ? QSCALE : 1.f;
        const u32 lo = packh2(d[0] * sc, d[1] * sc);
        const u32 hi = packh2(d[2] * sc, d[3] * sc);
        if (valid) {
            u32* dst = (m == 0 ? qg : (m == 1 ? kg : vg)) + qpl;
            dst[0] = lo;
            dst[1] = hi;
        }
    }
}

// ---- K_attn v2: WG = 256 thr (4 waves); wave = one qt-pair of (window, head).
// Grid = 343*2*3 (3 WGs cover the 11 qt-pairs). Small LDS (K[352][8] +
// V^T[8][360] f16, no Q staging) -> ~6 waves/SIMD hides the bias-load chain.
// Zero-pad k-slots/rows synthesized in registers (A,B both zero => no effect).
__global__ __launch_bounds__(256, 6) void k_attn(
    const u32* __restrict__ qg,
    const u32* __restrict__ kg,
    const u32* __restrict__ vg,
    float* __restrict__ og,
    const __fp16* __restrict__ bexp_blk)   // this block's [2][22][22][256] f16 tiles
{
    __shared__ u32 Kl[NPAD][4];       // f16 [352][8]
    __shared__ __fp16 Vt[8][360];     // dims x keys (padded stride)

    const int tid = threadIdx.x;
    const int pidx = blockIdx.x;
    const int grp = pidx % 3;
    const int rest = pidx / 3;
    const int h = rest & 1;
    const int w = rest >> 1;
    const int wh = w * 2 + h;
    const size_t qpl = (size_t)wh * QPLANE;

    for (int i = tid; i < NPAD; i += 256) {
        if (i < NWTOK) {
            *(uint4*)&Kl[i][0] = ((const uint4*)(kg + qpl))[i];
            const uint4 vw = ((const uint4*)(vg + qpl))[i];
            const h2 v01 = __builtin_bit_cast(h2, vw.x);
            const h2 v23 = __builtin_bit_cast(h2, vw.y);
            const h2 v45 = __builtin_bit_cast(h2, vw.z);
            const h2 v67 = __builtin_bit_cast(h2, vw.w);
            Vt[0][i] = v01.x; Vt[1][i] = v01.y;
            Vt[2][i] = v23.x; Vt[3][i] = v23.y;
            Vt[4][i] = v45.x; Vt[5][i] = v45.y;
            Vt[6][i] = v67.x; Vt[7][i] = v67.y;
        } else {
            *(uint4*)&Kl[i][0] = make_uint4(0, 0, 0, 0);
            #pragma unroll
            for (int d = 0; d < 8; ++d) Vt[d][i] = (__fp16)0.f;
        }
    }
    __syncthreads();

    const int wv = tid >> 6;
    const int p = grp * 4 + wv;       // qt-pair index
    if (p >= 11) return;

    const int lane = tid & 63;
    const int n = lane & 15;
    const int g4 = (lane >> 4) * 4;
    const h4 zeroh = __builtin_bit_cast(h4, make_uint2(0u, 0u));

    const int qiA = (2 * p) * 16 + n;   // always < 343 for p <= 10
    const int qiB = qiA + 16;           // may exceed 342 for p == 10
    h4 bqA = zeroh, bqB = zeroh;
    if (g4 < 8) {
        bqA = __builtin_bit_cast(h4, *(const uint2*)(qg + qpl + qiA * 4 + (g4 >> 1)));
        if (qiB < NWTOK)
            bqB = __builtin_bit_cast(h4, *(const uint2*)(qg + qpl + qiB * 4 + (g4 >> 1)));
    }

    const int laneoff = n * 16 + g4;
    const __fp16* trowA = bexp_blk + ((size_t)(h * 484) + (size_t)(2 * p) * NTILE) * 256 + laneoff;
    const __fp16* trowB = trowA + (size_t)NTILE * 256;

    f32x4 accA = {0.f, 0.f, 0.f, 0.f};
    f32x4 accB = {0.f, 0.f, 0.f, 0.f};
    float lA = 0.f, lB = 0.f;

    #pragma unroll
    for (int kt = 0; kt < NTILE; ++kt) {
        const uint2 cbA16 = *(const uint2*)(trowA + kt * 256);
        const uint2 cbB16 = *(const uint2*)(trowB + kt * 256);
        const h2 alo = __builtin_bit_cast(h2, cbA16.x);
        const h2 ahi = __builtin_bit_cast(h2, cbA16.y);
        const h2 blo = __builtin_bit_cast(h2, cbB16.x);
        const h2 bhi = __builtin_bit_cast(h2, cbB16.y);
        f32x4 cbAf, cbBf;
        cbAf[0] = (float)alo.x; cbAf[1] = (float)alo.y;
        cbAf[2] = (float)ahi.x; cbAf[3] = (float)ahi.y;
        cbBf[0] = (float)blo.x; cbBf[1] = (float)blo.y;
        cbBf[2] = (float)bhi.x; cbBf[3] = (float)bhi.y;

        h4 ak = zeroh;
        if (g4 < 8)
            ak = __builtin_bit_cast(h4, *(const uint2*)(&Kl[kt * 16 + n][g4 >> 1]));
        h4 av = zeroh;
        if (n < 8)
            av = *(const h4*)&Vt[n][kt * 16 + g4];

        f32x4 sA = __builtin_amdgcn_mfma_f32_16x16x16f16(ak, bqA, cbAf, 0, 0, 0);
        f32x4 sB = __builtin_amdgcn_mfma_f32_16x16x16f16(ak, bqB, cbBf, 0, 0, 0);

        const float pA0 = fast_exp2(sA[0]);
        const float pA1 = fast_exp2(sA[1]);
        const float pA2 = fast_exp2(sA[2]);
        const float pA3 = fast_exp2(sA[3]);
        const float pB0 = fast_exp2(sB[0]);
        const float pB1 = fast_exp2(sB[1]);
        const float pB2 = fast_exp2(sB[2]);
        const float pB3 = fast_exp2(sB[3]);
        lA += (pA0 + pA1) + (pA2 + pA3);
        lB += (pB0 + pB1) + (pB2 + pB3);

        const h4 bpA = packh4(pA0, pA1, pA2, pA3);
        const h4 bpB = packh4(pB0, pB1, pB2, pB3);
        accA = __builtin_amdgcn_mfma_f32_16x16x16f16(av, bpA, accA, 0, 0, 0);
        accB = __builtin_amdgcn_mfma_f32_16x16x16f16(av, bpB, accB, 0, 0, 0);
    }

    lA += __shfl_xor(lA, 16); lA += __shfl_xor(lA, 32);
    lB += __shfl_xor(lB, 16); lB += __shfl_xor(lB, 32);

    if (g4 < 8) {
        {
            const f32x4 o = accA * (1.f / lA);
            *(f32x4*)(og + (size_t)wh * OPLANE + qiA * 8 + g4) = o;
        }
        if (qiB < NWTOK) {
            const f32x4 o = accB * (1.f / lB);
            *(f32x4*)(og + (size_t)wh * OPLANE + qiB * 8 + g4) = o;
        }
    }
}

// ------- K_post (MFMA): wave = one (window, qt) tile of 16 tokens -------
__global__ __launch_bounds__(256, 4) void k_post(
    float* __restrict__ xe,
    const float* __restrict__ og,
    u32* __restrict__ qg,
    u32* __restrict__ kg,
    u32* __restrict__ vg,
    const float* __restrict__ proj_w,
    const float* __restrict__ proj_b,
    const float* __restrict__ n2_g,
    const float* __restrict__ n2_b,
    const float* __restrict__ fc1_w,
    const float* __restrict__ fc1_b,
    const float* __restrict__ fc2_w,
    const float* __restrict__ fc2_b,
    const float* __restrict__ n1_g_nx,
    const float* __restrict__ n1_b_nx,
    const float* __restrict__ qkv_w_nx,
    float* __restrict__ outp,
    const int last)
{
    __shared__ u32 projh[128];     // (16,16) f16: row*8 + k/2
    __shared__ u32 fc1h[512];      // (64,16) f16
    __shared__ u32 fc2h[512];      // (16,64) f16: row*32 + k/2
    __shared__ u32 qkvh[384];      // (48,16) f16
    __shared__ float projb_s[16], n2g_s[16], n2b_s[16], fc2b_s[16], n1g_s[16], n1b_s[16];
    __shared__ float fc1b_s[64];
    const int tid = threadIdx.x;
    if (tid < 128) {
        const float2 p = ((const float2*)proj_w)[tid];
        projh[tid] = packh2(p.x, p.y);
    }
    for (int i = tid; i < 512; i += 256) {
        const float2 a = ((const float2*)fc1_w)[i];
        fc1h[i] = packh2(a.x, a.y);
        const float2 b = ((const float2*)fc2_w)[i];
        fc2h[i] = packh2(b.x, b.y);
    }
    for (int i = tid; i < 384; i += 256) {
        const float2 a = ((const float2*)qkv_w_nx)[i];
        qkvh[i] = packh2(a.x, a.y);
    }
    if (tid < 16) {
        projb_s[tid] = proj_b[tid];
        n2g_s[tid] = n2_g[tid]; n2b_s[tid] = n2_b[tid];
        fc2b_s[tid] = fc2_b[tid];
        n1g_s[tid] = n1_g_nx[tid]; n1b_s[tid] = n1_b_nx[tid];
    }
    if (tid < 64) fc1b_s[tid] = fc1_b[tid];
    __syncthreads();

    const int wave_id = blockIdx.x * 4 + (tid >> 6);
    if (wave_id >= NWTOK * NTILE) return;   // 7546 tiles
    const int w = wave_id / NTILE;
    const int qt = wave_id - w * NTILE;

    const int lane = tid & 63;
    const int tcol = lane & 15;             // token column (also A row index)
    const int g4 = (lane >> 4) * 4;         // channel group base
    const int tok = qt * 16 + tcol;
    const bool valid = (tok < NWTOK);
    const int tokc = valid ? tok : (NWTOK - 1);

    const f32x4 zero = {0.f, 0.f, 0.f, 0.f};

    // ---- B-frag: o^T (ch g4..g4+3 of this token) ----
    const int pl = g4 >> 3;                 // head plane
    const int po = g4 & 7;                  // within-plane ch offset (0 or 4)
    const float4 o4 = *(const float4*)(og + (size_t)(w * 2 + pl) * OPLANE + tokc * 8 + po);
    const h4 oB = packh4(o4.x, o4.y, o4.z, o4.w);

    // ---- proj + residual + bias ----
    const uint2 apw = *(const uint2*)(projh + tcol * 8 + (g4 >> 1));
    const f32x4 d1 = __builtin_amdgcn_mfma_f32_16x16x16f16(
        __builtin_bit_cast(h4, apw), oB, zero, 0, 0, 0);
    const float4 xe4 = *(const float4*)(xe + (size_t)(w * NWTOK + tokc) * 16 + g4);
    const float4 pb4 = *(const float4*)(projb_s + g4);
    float xr0 = d1[0] + xe4.x + pb4.x;
    float xr1 = d1[1] + xe4.y + pb4.y;
    float xr2 = d1[2] + xe4.z + pb4.z;
    float xr3 = d1[3] + xe4.w + pb4.w;

    // ---- LN2 (cross-lane over channel groups) ----
    float s = (xr0 + xr1) + (xr2 + xr3);
    s += __shfl_xor(s, 16); s += __shfl_xor(s, 32);
    float mu = s * 0.0625f;
    float v0 = xr0 - mu, v1 = xr1 - mu, v2 = xr2 - mu, v3 = xr3 - mu;
    float vv = fmaf(v0, v0, fmaf(v1, v1, fmaf(v2, v2, v3 * v3)));
    vv += __shfl_xor(vv, 16); vv += __shfl_xor(vv, 32);
    float rs = rsqrtf(vv * 0.0625f + 1e-5f);
    const float4 g2 = *(const float4*)(n2g_s + g4);
    const float4 b2 = *(const float4*)(n2b_s + g4);
    const h4 zB = packh4(v0 * rs * g2.x + b2.x, v1 * rs * g2.y + b2.y,
                         v2 * rs * g2.z + b2.z, v3 * rs * g2.w + b2.w);

    // ---- fc1 (4 MFMAs) + bias + GELU -> 4 B-frags ----
    h4 hB[4];
    #pragma unroll
    for (int i = 0; i < 4; ++i) {
        const uint2 aw = *(const uint2*)(fc1h + (i * 16 + tcol) * 8 + (g4 >> 1));
        f32x4 hd = __builtin_amdgcn_mfma_f32_16x16x16f16(
            __builtin_bit_cast(h4, aw), zB, zero, 0, 0, 0);
        const float4 fb = *(const float4*)(fc1b_s + i * 16 + g4);
        hB[i] = packh4(gelu_exact(hd[0] + fb.x), gelu_exact(hd[1] + fb.y),
                       gelu_exact(hd[2] + fb.z), gelu_exact(hd[3] + fb.w));
    }

    // ---- fc2 (K=64: 4 chained MFMAs) + bias + residual ----
    f32x4 acc = zero;
    #pragma unroll
    for (int j = 0; j < 4; ++j) {
        const uint2 aw = *(const uint2*)(fc2h + tcol * 32 + ((j * 16 + g4) >> 1));
        acc = __builtin_amdgcn_mfma_f32_16x16x16f16(
            __builtin_bit_cast(h4, aw), hB[j], acc, 0, 0, 0);
    }
    const float4 f2b = *(const float4*)(fc2b_s + g4);
    xr0 += acc[0] + f2b.x;
    xr1 += acc[1] + f2b.y;
    xr2 += acc[2] + f2b.z;
    xr3 += acc[3] + f2b.w;

    if (last) {
        if (valid) {
            const int wd = w / 49, wr2 = w - wd * 49, whh = wr2 / 7, www = wr2 - whh * 7;
            const int tz = tok / 49, tr2 = tok - tz * 49, ty = tr2 / 7, tx = tr2 - ty * 7;
            const int g = ((wd * 7 + tz) * 49 + (whh * 7 + ty)) * 49 + (www * 7 + tx);
            outp[(size_t)(g4 + 0) * NTOK + g] = xr0;
            outp[(size_t)(g4 + 1) * NTOK + g] = xr1;
            outp[(size_t)(g4 + 2) * NTOK + g] = xr2;
            outp[(size_t)(g4 + 3) * NTOK + g] = xr3;
        }
        return;
    }

    if (valid) {
        float4 st = make_float4(xr0, xr1, xr2, xr3);
        *(float4*)(xe + (size_t)(w * NWTOK + tok) * 16 + g4) = st;
    }

    // ---- LN1 ----
    s = (xr0 + xr1) + (xr2 + xr3);
    s += __shfl_xor(s, 16); s += __shfl_xor(s, 32);
    mu = s * 0.0625f;
    v0 = xr0 - mu; v1 = xr1 - mu; v2 = xr2 - mu; v3 = xr3 - mu;
    vv = fmaf(v0, v0, fmaf(v1, v1, fmaf(v2, v2, v3 * v3)));
    vv += __shfl_xor(vv, 16); vv += __shfl_xor(vv, 32);
    rs = rsqrtf(vv * 0.0625f + 1e-5f);
    const float4 g1 = *(const float4*)(n1g_s + g4);
    const float4 b1 = *(const float4*)(n1b_s + g4);
    const h4 yB = packh4(v0 * rs * g1.x + b1.x, v1 * rs * g1.y + b1.y,
                         v2 * rs * g1.z + b1.z, v3 * rs * g1.w + b1.w);

    // ---- QKV for next block (3 MFMAs), store f16 rows ----
    const int head = g4 >> 3;
    const int uoff = (g4 & 7) >> 1;         // u32 offset within the token's 4-u32 row
    const size_t qpl = (size_t)(w * 2 + head) * QPLANE + tok * 4 + uoff;
    #pragma unroll
    for (int m = 0; m < 3; ++m) {
        const uint2 aw = *(const uint2*)(qkvh + (m * 16 + tcol) * 8 + (g4 >> 1));
        f32x4 d = __builtin_amdgcn_mfma_f32_16x16x16f16(
            __builtin_bit_cast(h4, aw), yB, zero, 0, 0, 0);
        float sc = (m == 0) ? QSCALE : 1.f;
        const u32 lo = packh2(d[0] * sc, d[1] * sc);
        const u32 hi = packh2(d[2] * sc, d[3] * sc);
        if (valid) {
            u32* dst = (m == 0 ? qg : (m == 1 ? kg : vg)) + qpl;
            dst[0] = lo;
            dst[1] = hi;
        }
    }
}

extern "C" void kernel_launch(void* const* d_in, const int* in_sizes, int n_in,
                              void* d_out, int out_size, void* d_ws, size_t ws_size,
                              hipStream_t stream) {
    const float* x       = (const float*)d_in[0];
    const float* pe_w    = (const float*)d_in[1];
    const float* pe_bias = (const float*)d_in[2];
    const float* pe_g    = (const float*)d_in[3];
    const float* pe_b    = (const float*)d_in[4];
    const float* n1_g    = (const float*)d_in[5];
    const float* n1_b    = (const float*)d_in[6];
    const float* qkv_w   = (const float*)d_in[7];
    const float* rpb     = (const float*)d_in[8];
    const float* proj_w  = (const float*)d_in[9];
    const float* proj_b  = (const float*)d_in[10];
    const float* n2_g    = (const float*)d_in[11];
    const float* n2_b    = (const float*)d_in[12];
    const float* fc1_w   = (const float*)d_in[13];
    const float* fc1_b   = (const float*)d_in[14];
    const float* fc2_w   = (const float*)d_in[15];
    const float* fc2_b   = (const float*)d_in[16];

    float* ws = (float*)d_ws;
    const size_t SEG = (size_t)NTOK * 16;     // 1,882,384 floats
    const size_t QSEG = (size_t)686 * QPLANE; // 941,192 u32
    float* xe = ws;
    u32* qg = (u32*)(ws + SEG);
    u32* kg = qg + QSEG;
    u32* vg = kg + QSEG;
    float* og = (float*)(vg + QSEG);                  // 686*2744 f32
    __fp16* bexp16 = (__fp16*)(og + (size_t)686 * OPLANE); // 6*484*256 f16
    float* out = (float*)d_out;

    const int k0_grid = NBIAS_BLK + (NK0_TILE + 3) / 4;   // bias tiles + k0 tiles
    k0_fused<<<k0_grid, 256, 0, stream>>>(
        x, pe_w, pe_bias, pe_g, pe_b, n1_g, n1_b, qkv_w, rpb,
        xe, qg, kg, vg, bexp16);

    const int attn_grid = NWTOK * 2 * 3;              // (window, head) x 3 qt-groups
    const int post_grid = (NWTOK * NTILE + 3) / 4;    // 7546 tiles, 4 waves/WG
    for (int i = 0; i < 3; ++i) {
        const int last = (i == 2) ? 1 : 0;
        const int nx = last ? i : i + 1;
        k_attn<<<attn_grid, 256, 0, stream>>>(
            qg, kg, vg, og, bexp16 + (size_t)i * 2 * 484 * 256);
        k_post<<<post_grid, 256, 0, stream>>>(
            xe, og, qg, kg, vg,
            proj_w + (size_t)i * 256, proj_b + (size_t)i * 16,
            n2_g + (size_t)i * 16, n2_b + (size_t)i * 16,
            fc1_w + (size_t)i * 1024, fc1_b + (size_t)i * 64,
            fc2_w + (size_t)i * 1024, fc2_b + (size_t)i * 16,
            n1_g + (size_t)nx * 16, n1_b + (size_t)nx * 16,
            qkv_w + (size_t)nx * 768,
            out, last);
    }
}

// Round 18
// 257.103 us; speedup vs baseline: 1.2194x; 1.2194x over previous
//
#include <hip/hip_runtime.h>
#include <math.h>

#define NWTOK 343
#define NTOK 117649
#define QSCALE 0.510069734f   // (1/sqrt(8)) * log2(e)
#define LOG2E 1.4426950408889634f
#define QPLANE 1372   // u32 per (window,head) plane of f16 rows
#define OPLANE 2744   // f32 per (window,head) plane of o
#define NPAD 352
#define NTILE 22
#define NBIAS_BLK 2904        // 6*22*22 bias tiles
#define NK0_TILE 7546         // 343*22 token tiles

typedef unsigned int u32;
typedef __fp16 h2 __attribute__((ext_vector_type(2)));
typedef __fp16 h4 __attribute__((ext_vector_type(4)));
typedef float f32x4 __attribute__((ext_vector_type(4)));

__device__ __forceinline__ u32 packh2(float a, float b) {
    h2 h = __builtin_amdgcn_cvt_pkrtz(a, b);
    return __builtin_bit_cast(u32, h);
}
__device__ __forceinline__ h4 packh4(float a, float b, float c, float d) {
    return __builtin_bit_cast(h4, make_uint2(packh2(a, b), packh2(c, d)));
}
__device__ __forceinline__ float fast_exp2(float x) {
#if __has_builtin(__builtin_amdgcn_exp2f)
    return __builtin_amdgcn_exp2f(x);
#else
    return exp2f(x);
#endif
}

// Inline exact-GELU via Abramowitz-Stegun 7.1.26 erf (max abs err 1.5e-7).
__device__ __forceinline__ float gelu_exact(float x) {
    const float z = x * 0.70710678118654752f;
    const float az = fabsf(z);
    const float t = __builtin_amdgcn_rcpf(fmaf(0.3275911f, az, 1.0f));
    float y = fmaf(t, 1.061405429f, -1.453152027f);
    y = fmaf(t, y, 1.421413741f);
    y = fmaf(t, y, -0.284496736f);
    y = fmaf(t, y, 0.254829592f);
    y *= t;
    const float one_m_erf = y * __expf(-az * az);
    const float erf_az = 1.0f - one_m_erf;
    const float erf_z = (z < 0.f) ? -erf_az : erf_az;
    return 0.5f * x * (1.0f + erf_z);
}

// ---- K0 fused: blocks [0,2904) expand bias tiles; blocks >= 2904 do
// patch-embed + LN + LN1 + QKV(block 0) in the MFMA tile structure. ----
__global__ __launch_bounds__(256, 4) void k0_fused(
    const float* __restrict__ x,
    const float* __restrict__ pe_w,
    const float* __restrict__ pe_bias,
    const float* __restrict__ pe_g,
    const float* __restrict__ pe_b,
    const float* __restrict__ n1_g,
    const float* __restrict__ n1_b,
    const float* __restrict__ qkv_w,
    const float* __restrict__ rpb,     // (3, 2197, 2)
    float* __restrict__ xe,
    u32* __restrict__ qg,
    u32* __restrict__ kg,
    u32* __restrict__ vg,
    __fp16* __restrict__ bexp16)
{
    const int tid = threadIdx.x;

    if (blockIdx.x < NBIAS_BLK) {
        const int tile = blockIdx.x;
        const int kt = tile % NTILE;
        const int rest = tile / NTILE;
        const int qt = rest % NTILE;
        const int bh = rest / NTILE;
        const int blk = bh >> 1, h = bh & 1;
        const int n = tid >> 4, g = tid & 15;
        const int i = qt * 16 + n, j = kt * 16 + g;
        float val;
        if (j >= NWTOK) {
            val = -60.f;
        } else if (i >= NWTOK) {
            val = 0.f;
        } else {
            const int iz = i / 49, ir = i - iz * 49, iy = ir / 7, ix = ir - iy * 7;
            const int jz = j / 49, jr = j - jz * 49, jy = jr / 7, jx = jr - jy * 7;
            const int idx = (iz - jz + 6) * 169 + (iy - jy + 6) * 13 + (ix - jx + 6);
            val = rpb[((size_t)blk * 2197 + idx) * 2 + h] * LOG2E;
        }
        bexp16[(size_t)tile * 256 + tid] = (__fp16)val;
        return;
    }

    __shared__ float pw_s[128];
    __shared__ u32 qkvh[384];
    __shared__ float pb_s[16], g_s[16], b_s[16], n1g_s[16], n1b_s[16];

    if (tid < 128) pw_s[tid] = pe_w[tid];
    for (int i = tid; i < 384; i += 256) {
        const float2 a = ((const float2*)qkv_w)[i];
        qkvh[i] = packh2(a.x, a.y);
    }
    if (tid < 16) {
        pb_s[tid] = pe_bias[tid]; g_s[tid] = pe_g[tid]; b_s[tid] = pe_b[tid];
        n1g_s[tid] = n1_g[tid]; n1b_s[tid] = n1_b[tid];
    }
    __syncthreads();

    const int wave_id = (blockIdx.x - NBIAS_BLK) * 4 + (tid >> 6);
    if (wave_id >= NK0_TILE) return;
    const int w = wave_id / NTILE;
    const int qt = wave_id - w * NTILE;

    const int lane = tid & 63;
    const int tcol = lane & 15;
    const int g4 = (lane >> 4) * 4;
    const int tok = qt * 16 + tcol;
    const bool valid = (tok < NWTOK);
    const int tokc = valid ? tok : (NWTOK - 1);

    const int wd = w / 49, wr = w - wd * 49, wh = wr / 7, ww = wr - wh * 7;
    const int tz = tokc / 49, tr = tokc - tz * 49, ty = tr / 7, tx = tr - ty * 7;
    const int z = wd * 7 + tz, y = wh * 7 + ty, xx = ww * 7 + tx;
    const float* bp = x + ((size_t)(2 * z) * 98 + (2 * y)) * 98 + 2 * xx;
    float in[8];
    in[0] = bp[0];    in[1] = bp[1];
    in[2] = bp[98];   in[3] = bp[99];
    in[4] = bp[9604]; in[5] = bp[9605];
    in[6] = bp[9702]; in[7] = bp[9703];

    float c4[4];
    #pragma unroll
    for (int i = 0; i < 4; ++i) {
        const int ch = g4 + i;
        const float4 w0 = *(const float4*)(pw_s + ch * 8);
        const float4 w1 = *(const float4*)(pw_s + ch * 8 + 4);
        float a = pb_s[ch];
        a = fmaf(in[0], w0.x, a); a = fmaf(in[1], w0.y, a);
        a = fmaf(in[2], w0.z, a); a = fmaf(in[3], w0.w, a);
        a = fmaf(in[4], w1.x, a); a = fmaf(in[5], w1.y, a);
        a = fmaf(in[6], w1.z, a); a = fmaf(in[7], w1.w, a);
        c4[i] = a;
    }

    float s = (c4[0] + c4[1]) + (c4[2] + c4[3]);
    s += __shfl_xor(s, 16); s += __shfl_xor(s, 32);
    float mu = s * 0.0625f;
    float v0 = c4[0] - mu, v1 = c4[1] - mu, v2 = c4[2] - mu, v3 = c4[3] - mu;
    float vv = fmaf(v0, v0, fmaf(v1, v1, fmaf(v2, v2, v3 * v3)));
    vv += __shfl_xor(vv, 16); vv += __shfl_xor(vv, 32);
    float rs = rsqrtf(vv * 0.0625f + 1e-5f);
    const float4 gg = *(const float4*)(g_s + g4);
    const float4 bb = *(const float4*)(b_s + g4);
    const float o0 = v0 * rs * gg.x + bb.x;
    const float o1 = v1 * rs * gg.y + bb.y;
    const float o2 = v2 * rs * gg.z + bb.z;
    const float o3 = v3 * rs * gg.w + bb.w;

    if (valid)
        *(float4*)(xe + (size_t)(w * NWTOK + tok) * 16 + g4) = make_float4(o0, o1, o2, o3);

    s = (o0 + o1) + (o2 + o3);
    s += __shfl_xor(s, 16); s += __shfl_xor(s, 32);
    mu = s * 0.0625f;
    v0 = o0 - mu; v1 = o1 - mu; v2 = o2 - mu; v3 = o3 - mu;
    vv = fmaf(v0, v0, fmaf(v1, v1, fmaf(v2, v2, v3 * v3)));
    vv += __shfl_xor(vv, 16); vv += __shfl_xor(vv, 32);
    rs = rsqrtf(vv * 0.0625f + 1e-5f);
    const float4 g1 = *(const float4*)(n1g_s + g4);
    const float4 b1 = *(const float4*)(n1b_s + g4);
    const h4 yB = packh4(v0 * rs * g1.x + b1.x, v1 * rs * g1.y + b1.y,
                         v2 * rs * g1.z + b1.z, v3 * rs * g1.w + b1.w);

    const f32x4 zero = {0.f, 0.f, 0.f, 0.f};
    const int head = g4 >> 3;
    const int uoff = (g4 & 7) >> 1;
    const size_t qpl = (size_t)(w * 2 + head) * QPLANE + tok * 4 + uoff;
    #pragma unroll
    for (int m = 0; m < 3; ++m) {
        const uint2 aw = *(const uint2*)(qkvh + (m * 16 + tcol) * 8 + (g4 >> 1));
        f32x4 d = __builtin_amdgcn_mfma_f32_16x16x16f16(
            __builtin_bit_cast(h4, aw), yB, zero, 0, 0, 0);
        const float sc = (m == 0) ? QSCALE : 1.f;
        const u32 lo = packh2(d[0] * sc, d[1] * sc);
        const u32 hi = packh2(d[2] * sc, d[3] * sc);
        if (valid) {
            u32* dst = (m == 0 ? qg : (m == 1 ? kg : vg)) + qpl;
            dst[0] = lo;
            dst[1] = hi;
        }
    }
}

// ---- K_attn v2: WG = 256 thr (4 waves); wave = one qt-pair of (window, head).
// Grid = 343*2*3. Small LDS; launch_bounds(256,4) so the unrolled kt loop
// keeps its hoisted loads in registers (R17's (256,6) cap forced scratch
// spills -> 360 MB/dispatch of spill traffic).
__global__ __launch_bounds__(256, 4) void k_attn(
    const u32* __restrict__ qg,
    const u32* __restrict__ kg,
    const u32* __restrict__ vg,
    float* __restrict__ og,
    const __fp16* __restrict__ bexp_blk)   // this block's [2][22][22][256] f16 tiles
{
    __shared__ u32 Kl[NPAD][4];       // f16 [352][8]
    __shared__ __fp16 Vt[8][360];     // dims x keys (padded stride)

    const int tid = threadIdx.x;
    const int pidx = blockIdx.x;
    const int grp = pidx % 3;
    const int rest = pidx / 3;
    const int h = rest & 1;
    const int w = rest >> 1;
    const int wh = w * 2 + h;
    const size_t qpl = (size_t)wh * QPLANE;

    for (int i = tid; i < NPAD; i += 256) {
        if (i < NWTOK) {
            *(uint4*)&Kl[i][0] = ((const uint4*)(kg + qpl))[i];
            const uint4 vw = ((const uint4*)(vg + qpl))[i];
            const h2 v01 = __builtin_bit_cast(h2, vw.x);
            const h2 v23 = __builtin_bit_cast(h2, vw.y);
            const h2 v45 = __builtin_bit_cast(h2, vw.z);
            const h2 v67 = __builtin_bit_cast(h2, vw.w);
            Vt[0][i] = v01.x; Vt[1][i] = v01.y;
            Vt[2][i] = v23.x; Vt[3][i] = v23.y;
            Vt[4][i] = v45.x; Vt[5][i] = v45.y;
            Vt[6][i] = v67.x; Vt[7][i] = v67.y;
        } else {
            *(uint4*)&Kl[i][0] = make_uint4(0, 0, 0, 0);
            #pragma unroll
            for (int d = 0; d < 8; ++d) Vt[d][i] = (__fp16)0.f;
        }
    }
    __syncthreads();

    const int wv = tid >> 6;
    const int p = grp * 4 + wv;       // qt-pair index
    if (p >= 11) return;

    const int lane = tid & 63;
    const int n = lane & 15;
    const int g4 = (lane >> 4) * 4;
    const h4 zeroh = __builtin_bit_cast(h4, make_uint2(0u, 0u));

    const int qiA = (2 * p) * 16 + n;   // always < 343 for p <= 10
    const int qiB = qiA + 16;           // may exceed 342 for p == 10
    h4 bqA = zeroh, bqB = zeroh;
    if (g4 < 8) {
        bqA = __builtin_bit_cast(h4, *(const uint2*)(qg + qpl + qiA * 4 + (g4 >> 1)));
        if (qiB < NWTOK)
            bqB = __builtin_bit_cast(h4, *(const uint2*)(qg + qpl + qiB * 4 + (g4 >> 1)));
    }

    const int laneoff = n * 16 + g4;
    const __fp16* trowA = bexp_blk + ((size_t)(h * 484) + (size_t)(2 * p) * NTILE) * 256 + laneoff;
    const __fp16* trowB = trowA + (size_t)NTILE * 256;

    f32x4 accA = {0.f, 0.f, 0.f, 0.f};
    f32x4 accB = {0.f, 0.f, 0.f, 0.f};
    float lA = 0.f, lB = 0.f;

    #pragma unroll
    for (int kt = 0; kt < NTILE; ++kt) {
        const uint2 cbA16 = *(const uint2*)(trowA + kt * 256);
        const uint2 cbB16 = *(const uint2*)(trowB + kt * 256);
        const h2 alo = __builtin_bit_cast(h2, cbA16.x);
        const h2 ahi = __builtin_bit_cast(h2, cbA16.y);
        const h2 blo = __builtin_bit_cast(h2, cbB16.x);
        const h2 bhi = __builtin_bit_cast(h2, cbB16.y);
        f32x4 cbAf, cbBf;
        cbAf[0] = (float)alo.x; cbAf[1] = (float)alo.y;
        cbAf[2] = (float)ahi.x; cbAf[3] = (float)ahi.y;
        cbBf[0] = (float)blo.x; cbBf[1] = (float)blo.y;
        cbBf[2] = (float)bhi.x; cbBf[3] = (float)bhi.y;

        h4 ak = zeroh;
        if (g4 < 8)
            ak = __builtin_bit_cast(h4, *(const uint2*)(&Kl[kt * 16 + n][g4 >> 1]));
        h4 av = zeroh;
        if (n < 8)
            av = *(const h4*)&Vt[n][kt * 16 + g4];

        f32x4 sA = __builtin_amdgcn_mfma_f32_16x16x16f16(ak, bqA, cbAf, 0, 0, 0);
        f32x4 sB = __builtin_amdgcn_mfma_f32_16x16x16f16(ak, bqB, cbBf, 0, 0, 0);

        const float pA0 = fast_exp2(sA[0]);
        const float pA1 = fast_exp2(sA[1]);
        const float pA2 = fast_exp2(sA[2]);
        const float pA3 = fast_exp2(sA[3]);
        const float pB0 = fast_exp2(sB[0]);
        const float pB1 = fast_exp2(sB[1]);
        const float pB2 = fast_exp2(sB[2]);
        const float pB3 = fast_exp2(sB[3]);
        lA += (pA0 + pA1) + (pA2 + pA3);
        lB += (pB0 + pB1) + (pB2 + pB3);

        const h4 bpA = packh4(pA0, pA1, pA2, pA3);
        const h4 bpB = packh4(pB0, pB1, pB2, pB3);
        accA = __builtin_amdgcn_mfma_f32_16x16x16f16(av, bpA, accA, 0, 0, 0);
        accB = __builtin_amdgcn_mfma_f32_16x16x16f16(av, bpB, accB, 0, 0, 0);
    }

    lA += __shfl_xor(lA, 16); lA += __shfl_xor(lA, 32);
    lB += __shfl_xor(lB, 16); lB += __shfl_xor(lB, 32);

    if (g4 < 8) {
        {
            const f32x4 o = accA * (1.f / lA);
            *(f32x4*)(og + (size_t)wh * OPLANE + qiA * 8 + g4) = o;
        }
        if (qiB < NWTOK) {
            const f32x4 o = accB * (1.f / lB);
            *(f32x4*)(og + (size_t)wh * OPLANE + qiB * 8 + g4) = o;
        }
    }
}

// ------- K_post (MFMA): wave = one (window, qt) tile of 16 tokens -------
__global__ __launch_bounds__(256, 4) void k_post(
    float* __restrict__ xe,
    const float* __restrict__ og,
    u32* __restrict__ qg,
    u32* __restrict__ kg,
    u32* __restrict__ vg,
    const float* __restrict__ proj_w,
    const float* __restrict__ proj_b,
    const float* __restrict__ n2_g,
    const float* __restrict__ n2_b,
    const float* __restrict__ fc1_w,
    const float* __restrict__ fc1_b,
    const float* __restrict__ fc2_w,
    const float* __restrict__ fc2_b,
    const float* __restrict__ n1_g_nx,
    const float* __restrict__ n1_b_nx,
    const float* __restrict__ qkv_w_nx,
    float* __restrict__ outp,
    const int last)
{
    __shared__ u32 projh[128];     // (16,16) f16: row*8 + k/2
    __shared__ u32 fc1h[512];      // (64,16) f16
    __shared__ u32 fc2h[512];      // (16,64) f16: row*32 + k/2
    __shared__ u32 qkvh[384];      // (48,16) f16
    __shared__ float projb_s[16], n2g_s[16], n2b_s[16], fc2b_s[16], n1g_s[16], n1b_s[16];
    __shared__ float fc1b_s[64];
    const int tid = threadIdx.x;
    if (tid < 128) {
        const float2 p = ((const float2*)proj_w)[tid];
        projh[tid] = packh2(p.x, p.y);
    }
    for (int i = tid; i < 512; i += 256) {
        const float2 a = ((const float2*)fc1_w)[i];
        fc1h[i] = packh2(a.x, a.y);
        const float2 b = ((const float2*)fc2_w)[i];
        fc2h[i] = packh2(b.x, b.y);
    }
    for (int i = tid; i < 384; i += 256) {
        const float2 a = ((const float2*)qkv_w_nx)[i];
        qkvh[i] = packh2(a.x, a.y);
    }
    if (tid < 16) {
        projb_s[tid] = proj_b[tid];
        n2g_s[tid] = n2_g[tid]; n2b_s[tid] = n2_b[tid];
        fc2b_s[tid] = fc2_b[tid];
        n1g_s[tid] = n1_g_nx[tid]; n1b_s[tid] = n1_b_nx[tid];
    }
    if (tid < 64) fc1b_s[tid] = fc1_b[tid];
    __syncthreads();

    const int wave_id = blockIdx.x * 4 + (tid >> 6);
    if (wave_id >= NWTOK * NTILE) return;   // 7546 tiles
    const int w = wave_id / NTILE;
    const int qt = wave_id - w * NTILE;

    const int lane = tid & 63;
    const int tcol = lane & 15;             // token column (also A row index)
    const int g4 = (lane >> 4) * 4;         // channel group base
    const int tok = qt * 16 + tcol;
    const bool valid = (tok < NWTOK);
    const int tokc = valid ? tok : (NWTOK - 1);

    const f32x4 zero = {0.f, 0.f, 0.f, 0.f};

    // ---- B-frag: o^T (ch g4..g4+3 of this token) ----
    const int pl = g4 >> 3;                 // head plane
    const int po = g4 & 7;                  // within-plane ch offset (0 or 4)
    const float4 o4 = *(const float4*)(og + (size_t)(w * 2 + pl) * OPLANE + tokc * 8 + po);
    const h4 oB = packh4(o4.x, o4.y, o4.z, o4.w);

    // ---- proj + residual + bias ----
    const uint2 apw = *(const uint2*)(projh + tcol * 8 + (g4 >> 1));
    const f32x4 d1 = __builtin_amdgcn_mfma_f32_16x16x16f16(
        __builtin_bit_cast(h4, apw), oB, zero, 0, 0, 0);
    const float4 xe4 = *(const float4*)(xe + (size_t)(w * NWTOK + tokc) * 16 + g4);
    const float4 pb4 = *(const float4*)(projb_s + g4);
    float xr0 = d1[0] + xe4.x + pb4.x;
    float xr1 = d1[1] + xe4.y + pb4.y;
    float xr2 = d1[2] + xe4.z + pb4.z;
    float xr3 = d1[3] + xe4.w + pb4.w;

    // ---- LN2 (cross-lane over channel groups) ----
    float s = (xr0 + xr1) + (xr2 + xr3);
    s += __shfl_xor(s, 16); s += __shfl_xor(s, 32);
    float mu = s * 0.0625f;
    float v0 = xr0 - mu, v1 = xr1 - mu, v2 = xr2 - mu, v3 = xr3 - mu;
    float vv = fmaf(v0, v0, fmaf(v1, v1, fmaf(v2, v2, v3 * v3)));
    vv += __shfl_xor(vv, 16); vv += __shfl_xor(vv, 32);
    float rs = rsqrtf(vv * 0.0625f + 1e-5f);
    const float4 g2 = *(const float4*)(n2g_s + g4);
    const float4 b2 = *(const float4*)(n2b_s + g4);
    const h4 zB = packh4(v0 * rs * g2.x + b2.x, v1 * rs * g2.y + b2.y,
                         v2 * rs * g2.z + b2.z, v3 * rs * g2.w + b2.w);

    // ---- fc1 (4 MFMAs) + bias + GELU -> 4 B-frags ----
    h4 hB[4];
    #pragma unroll
    for (int i = 0; i < 4; ++i) {
        const uint2 aw = *(const uint2*)(fc1h + (i * 16 + tcol) * 8 + (g4 >> 1));
        f32x4 hd = __builtin_amdgcn_mfma_f32_16x16x16f16(
            __builtin_bit_cast(h4, aw), zB, zero, 0, 0, 0);
        const float4 fb = *(const float4*)(fc1b_s + i * 16 + g4);
        hB[i] = packh4(gelu_exact(hd[0] + fb.x), gelu_exact(hd[1] + fb.y),
                       gelu_exact(hd[2] + fb.z), gelu_exact(hd[3] + fb.w));
    }

    // ---- fc2 (K=64: 4 chained MFMAs) + bias + residual ----
    f32x4 acc = zero;
    #pragma unroll
    for (int j = 0; j < 4; ++j) {
        const uint2 aw = *(const uint2*)(fc2h + tcol * 32 + ((j * 16 + g4) >> 1));
        acc = __builtin_amdgcn_mfma_f32_16x16x16f16(
            __builtin_bit_cast(h4, aw), hB[j], acc, 0, 0, 0);
    }
    const float4 f2b = *(const float4*)(fc2b_s + g4);
    xr0 += acc[0] + f2b.x;
    xr1 += acc[1] + f2b.y;
    xr2 += acc[2] + f2b.z;
    xr3 += acc[3] + f2b.w;

    if (last) {
        if (valid) {
            const int wd = w / 49, wr2 = w - wd * 49, whh = wr2 / 7, www = wr2 - whh * 7;
            const int tz = tok / 49, tr2 = tok - tz * 49, ty = tr2 / 7, tx = tr2 - ty * 7;
            const int g = ((wd * 7 + tz) * 49 + (whh * 7 + ty)) * 49 + (www * 7 + tx);
            outp[(size_t)(g4 + 0) * NTOK + g] = xr0;
            outp[(size_t)(g4 + 1) * NTOK + g] = xr1;
            outp[(size_t)(g4 + 2) * NTOK + g] = xr2;
            outp[(size_t)(g4 + 3) * NTOK + g] = xr3;
        }
        return;
    }

    if (valid) {
        float4 st = make_float4(xr0, xr1, xr2, xr3);
        *(float4*)(xe + (size_t)(w * NWTOK + tok) * 16 + g4) = st;
    }

    // ---- LN1 ----
    s = (xr0 + xr1) + (xr2 + xr3);
    s += __shfl_xor(s, 16); s += __shfl_xor(s, 32);
    mu = s * 0.0625f;
    v0 = xr0 - mu; v1 = xr1 - mu; v2 = xr2 - mu; v3 = xr3 - mu;
    vv = fmaf(v0, v0, fmaf(v1, v1, fmaf(v2, v2, v3 * v3)));
    vv += __shfl_xor(vv, 16); vv += __shfl_xor(vv, 32);
    rs = rsqrtf(vv * 0.0625f + 1e-5f);
    const float4 g1 = *(const float4*)(n1g_s + g4);
    const float4 b1 = *(const float4*)(n1b_s + g4);
    const h4 yB = packh4(v0 * rs * g1.x + b1.x, v1 * rs * g1.y + b1.y,
                         v2 * rs * g1.z + b1.z, v3 * rs * g1.w + b1.w);

    // ---- QKV for next block (3 MFMAs), store f16 rows ----
    const int head = g4 >> 3;
    const int uoff = (g4 & 7) >> 1;         // u32 offset within the token's 4-u32 row
    const size_t qpl = (size_t)(w * 2 + head) * QPLANE + tok * 4 + uoff;
    #pragma unroll
    for (int m = 0; m < 3; ++m) {
        const uint2 aw = *(const uint2*)(qkvh + (m * 16 + tcol) * 8 + (g4 >> 1));
        f32x4 d = __builtin_amdgcn_mfma_f32_16x16x16f16(
            __builtin_bit_cast(h4, aw), yB, zero, 0, 0, 0);
        float sc = (m == 0) ? QSCALE : 1.f;
        const u32 lo = packh2(d[0] * sc, d[1] * sc);
        const u32 hi = packh2(d[2] * sc, d[3] * sc);
        if (valid) {
            u32* dst = (m == 0 ? qg : (m == 1 ? kg : vg)) + qpl;
            dst[0] = lo;
            dst[1] = hi;
        }
    }
}

extern "C" void kernel_launch(void* const* d_in, const int* in_sizes, int n_in,
                              void* d_out, int out_size, void* d_ws, size_t ws_size,
                              hipStream_t stream) {
    const float* x       = (const float*)d_in[0];
    const float* pe_w    = (const float*)d_in[1];
    const float* pe_bias = (const float*)d_in[2];
    const float* pe_g    = (const float*)d_in[3];
    const float* pe_b    = (const float*)d_in[4];
    const float* n1_g    = (const float*)d_in[5];
    const float* n1_b    = (const float*)d_in[6];
    const float* qkv_w   = (const float*)d_in[7];
    const float* rpb     = (const float*)d_in[8];
    const float* proj_w  = (const float*)d_in[9];
    const float* proj_b  = (const float*)d_in[10];
    const float* n2_g    = (const float*)d_in[11];
    const float* n2_b    = (const float*)d_in[12];
    const float* fc1_w   = (const float*)d_in[13];
    const float* fc1_b   = (const float*)d_in[14];
    const float* fc2_w   = (const float*)d_in[15];
    const float* fc2_b   = (const float*)d_in[16];

    float* ws = (float*)d_ws;
    const size_t SEG = (size_t)NTOK * 16;     // 1,882,384 floats
    const size_t QSEG = (size_t)686 * QPLANE; // 941,192 u32
    float* xe = ws;
    u32* qg = (u32*)(ws + SEG);
    u32* kg = qg + QSEG;
    u32* vg = kg + QSEG;
    float* og = (float*)(vg + QSEG);                  // 686*2744 f32
    __fp16* bexp16 = (__fp16*)(og + (size_t)686 * OPLANE); // 6*484*256 f16
    float* out = (float*)d_out;

    const int k0_grid = NBIAS_BLK + (NK0_TILE + 3) / 4;   // bias tiles + k0 tiles
    k0_fused<<<k0_grid, 256, 0, stream>>>(
        x, pe_w, pe_bias, pe_g, pe_b, n1_g, n1_b, qkv_w, rpb,
        xe, qg, kg, vg, bexp16);

    const int attn_grid = NWTOK * 2 * 3;              // (window, head) x 3 qt-groups
    const int post_grid = (NWTOK * NTILE + 3) / 4;    // 7546 tiles, 4 waves/WG
    for (int i = 0; i < 3; ++i) {
        const int last = (i == 2) ? 1 : 0;
        const int nx = last ? i : i + 1;
        k_attn<<<attn_grid, 256, 0, stream>>>(
            qg, kg, vg, og, bexp16 + (size_t)i * 2 * 484 * 256);
        k_post<<<post_grid, 256, 0, stream>>>(
            xe, og, qg, kg, vg,
            proj_w + (size_t)i * 256, proj_b + (size_t)i * 16,
            n2_g + (size_t)i * 16, n2_b + (size_t)i * 16,
            fc1_w + (size_t)i * 1024, fc1_b + (size_t)i * 64,
            fc2_w + (size_t)i * 1024, fc2_b + (size_t)i * 16,
            n1_g + (size_t)nx * 16, n1_b + (size_t)nx * 16,
            qkv_w + (size_t)nx * 768,
            out, last);
    }
}

// Round 19
// 129.362 us; speedup vs baseline: 2.4234x; 1.9875x over previous
//
#include <hip/hip_runtime.h>
#include <math.h>

#define NWTOK 343
#define NTOK 117649
#define QSCALE 0.510069734f   // (1/sqrt(8)) * log2(e)
#define LOG2E 1.4426950408889634f
#define QPLANE 1372   // u32 per (window,head) plane of f16 rows
#define OPLANE 2744   // f32 per (window,head) plane of o
#define NPAD 352
#define NTILE 22
#define NBIAS_BLK 2904        // 6*22*22 bias tiles
#define NK0_TILE 7546         // 343*22 token tiles

typedef unsigned int u32;
typedef __fp16 h2 __attribute__((ext_vector_type(2)));
typedef __fp16 h4 __attribute__((ext_vector_type(4)));
typedef float f32x4 __attribute__((ext_vector_type(4)));

__device__ __forceinline__ u32 packh2(float a, float b) {
    h2 h = __builtin_amdgcn_cvt_pkrtz(a, b);
    return __builtin_bit_cast(u32, h);
}
__device__ __forceinline__ h4 packh4(float a, float b, float c, float d) {
    return __builtin_bit_cast(h4, make_uint2(packh2(a, b), packh2(c, d)));
}
__device__ __forceinline__ float fast_exp2(float x) {
#if __has_builtin(__builtin_amdgcn_exp2f)
    return __builtin_amdgcn_exp2f(x);
#else
    return exp2f(x);
#endif
}

// Inline exact-GELU via Abramowitz-Stegun 7.1.26 erf (max abs err 1.5e-7).
__device__ __forceinline__ float gelu_exact(float x) {
    const float z = x * 0.70710678118654752f;
    const float az = fabsf(z);
    const float t = __builtin_amdgcn_rcpf(fmaf(0.3275911f, az, 1.0f));
    float y = fmaf(t, 1.061405429f, -1.453152027f);
    y = fmaf(t, y, 1.421413741f);
    y = fmaf(t, y, -0.284496736f);
    y = fmaf(t, y, 0.254829592f);
    y *= t;
    const float one_m_erf = y * __expf(-az * az);
    const float erf_az = 1.0f - one_m_erf;
    const float erf_z = (z < 0.f) ? -erf_az : erf_az;
    return 0.5f * x * (1.0f + erf_z);
}

// ---- K0 fused: blocks [0,2904) expand bias tiles; blocks >= 2904 do
// patch-embed + LN + LN1 + QKV(block 0) in the MFMA tile structure. ----
__global__ __launch_bounds__(256, 4) void k0_fused(
    const float* __restrict__ x,
    const float* __restrict__ pe_w,
    const float* __restrict__ pe_bias,
    const float* __restrict__ pe_g,
    const float* __restrict__ pe_b,
    const float* __restrict__ n1_g,
    const float* __restrict__ n1_b,
    const float* __restrict__ qkv_w,
    const float* __restrict__ rpb,     // (3, 2197, 2)
    float* __restrict__ xe,
    u32* __restrict__ qg,
    u32* __restrict__ kg,
    u32* __restrict__ vg,
    __fp16* __restrict__ bexp16)
{
    const int tid = threadIdx.x;

    if (blockIdx.x < NBIAS_BLK) {
        const int tile = blockIdx.x;
        const int kt = tile % NTILE;
        const int rest = tile / NTILE;
        const int qt = rest % NTILE;
        const int bh = rest / NTILE;
        const int blk = bh >> 1, h = bh & 1;
        const int n = tid >> 4, g = tid & 15;
        const int i = qt * 16 + n, j = kt * 16 + g;
        float val;
        if (j >= NWTOK) {
            val = -60.f;
        } else if (i >= NWTOK) {
            val = 0.f;
        } else {
            const int iz = i / 49, ir = i - iz * 49, iy = ir / 7, ix = ir - iy * 7;
            const int jz = j / 49, jr = j - jz * 49, jy = jr / 7, jx = jr - jy * 7;
            const int idx = (iz - jz + 6) * 169 + (iy - jy + 6) * 13 + (ix - jx + 6);
            val = rpb[((size_t)blk * 2197 + idx) * 2 + h] * LOG2E;
        }
        bexp16[(size_t)tile * 256 + tid] = (__fp16)val;
        return;
    }

    __shared__ float pw_s[128];
    __shared__ u32 qkvh[384];
    __shared__ float pb_s[16], g_s[16], b_s[16], n1g_s[16], n1b_s[16];

    if (tid < 128) pw_s[tid] = pe_w[tid];
    for (int i = tid; i < 384; i += 256) {
        const float2 a = ((const float2*)qkv_w)[i];
        qkvh[i] = packh2(a.x, a.y);
    }
    if (tid < 16) {
        pb_s[tid] = pe_bias[tid]; g_s[tid] = pe_g[tid]; b_s[tid] = pe_b[tid];
        n1g_s[tid] = n1_g[tid]; n1b_s[tid] = n1_b[tid];
    }
    __syncthreads();

    const int wave_id = (blockIdx.x - NBIAS_BLK) * 4 + (tid >> 6);
    if (wave_id >= NK0_TILE) return;
    const int w = wave_id / NTILE;
    const int qt = wave_id - w * NTILE;

    const int lane = tid & 63;
    const int tcol = lane & 15;
    const int g4 = (lane >> 4) * 4;
    const int tok = qt * 16 + tcol;
    const bool valid = (tok < NWTOK);
    const int tokc = valid ? tok : (NWTOK - 1);

    const int wd = w / 49, wr = w - wd * 49, wh = wr / 7, ww = wr - wh * 7;
    const int tz = tokc / 49, tr = tokc - tz * 49, ty = tr / 7, tx = tr - ty * 7;
    const int z = wd * 7 + tz, y = wh * 7 + ty, xx = ww * 7 + tx;
    const float* bp = x + ((size_t)(2 * z) * 98 + (2 * y)) * 98 + 2 * xx;
    float in[8];
    in[0] = bp[0];    in[1] = bp[1];
    in[2] = bp[98];   in[3] = bp[99];
    in[4] = bp[9604]; in[5] = bp[9605];
    in[6] = bp[9702]; in[7] = bp[9703];

    float c4[4];
    #pragma unroll
    for (int i = 0; i < 4; ++i) {
        const int ch = g4 + i;
        const float4 w0 = *(const float4*)(pw_s + ch * 8);
        const float4 w1 = *(const float4*)(pw_s + ch * 8 + 4);
        float a = pb_s[ch];
        a = fmaf(in[0], w0.x, a); a = fmaf(in[1], w0.y, a);
        a = fmaf(in[2], w0.z, a); a = fmaf(in[3], w0.w, a);
        a = fmaf(in[4], w1.x, a); a = fmaf(in[5], w1.y, a);
        a = fmaf(in[6], w1.z, a); a = fmaf(in[7], w1.w, a);
        c4[i] = a;
    }

    float s = (c4[0] + c4[1]) + (c4[2] + c4[3]);
    s += __shfl_xor(s, 16); s += __shfl_xor(s, 32);
    float mu = s * 0.0625f;
    float v0 = c4[0] - mu, v1 = c4[1] - mu, v2 = c4[2] - mu, v3 = c4[3] - mu;
    float vv = fmaf(v0, v0, fmaf(v1, v1, fmaf(v2, v2, v3 * v3)));
    vv += __shfl_xor(vv, 16); vv += __shfl_xor(vv, 32);
    float rs = rsqrtf(vv * 0.0625f + 1e-5f);
    const float4 gg = *(const float4*)(g_s + g4);
    const float4 bb = *(const float4*)(b_s + g4);
    const float o0 = v0 * rs * gg.x + bb.x;
    const float o1 = v1 * rs * gg.y + bb.y;
    const float o2 = v2 * rs * gg.z + bb.z;
    const float o3 = v3 * rs * gg.w + bb.w;

    if (valid)
        *(float4*)(xe + (size_t)(w * NWTOK + tok) * 16 + g4) = make_float4(o0, o1, o2, o3);

    s = (o0 + o1) + (o2 + o3);
    s += __shfl_xor(s, 16); s += __shfl_xor(s, 32);
    mu = s * 0.0625f;
    v0 = o0 - mu; v1 = o1 - mu; v2 = o2 - mu; v3 = o3 - mu;
    vv = fmaf(v0, v0, fmaf(v1, v1, fmaf(v2, v2, v3 * v3)));
    vv += __shfl_xor(vv, 16); vv += __shfl_xor(vv, 32);
    rs = rsqrtf(vv * 0.0625f + 1e-5f);
    const float4 g1 = *(const float4*)(n1g_s + g4);
    const float4 b1 = *(const float4*)(n1b_s + g4);
    const h4 yB = packh4(v0 * rs * g1.x + b1.x, v1 * rs * g1.y + b1.y,
                         v2 * rs * g1.z + b1.z, v3 * rs * g1.w + b1.w);

    const f32x4 zero = {0.f, 0.f, 0.f, 0.f};
    const int head = g4 >> 3;
    const int uoff = (g4 & 7) >> 1;
    const size_t qpl = (size_t)(w * 2 + head) * QPLANE + tok * 4 + uoff;
    #pragma unroll
    for (int m = 0; m < 3; ++m) {
        const uint2 aw = *(const uint2*)(qkvh + (m * 16 + tcol) * 8 + (g4 >> 1));
        f32x4 d = __builtin_amdgcn_mfma_f32_16x16x16f16(
            __builtin_bit_cast(h4, aw), yB, zero, 0, 0, 0);
        const float sc = (m == 0) ? QSCALE : 1.f;
        const u32 lo = packh2(d[0] * sc, d[1] * sc);
        const u32 hi = packh2(d[2] * sc, d[3] * sc);
        if (valid) {
            u32* dst = (m == 0 ? qg : (m == 1 ? kg : vg)) + qpl;
            dst[0] = lo;
            dst[1] = hi;
        }
    }
}

// ---- K_attn v3: WG = 256 thr (4 waves); wave = one qt-pair x 2 WINDOWS.
// Window pairing shares each bias-tile load across 4 MFMA chains (R12's
// inner loop) while the small 2-window LDS (22.8 KB) + launch_bounds(256,4)
// keeps 4-5 WGs/CU resident (R18's packaging, no spill).
__global__ __launch_bounds__(256, 4) void k_attn(
    const u32* __restrict__ qg,
    const u32* __restrict__ kg,
    const u32* __restrict__ vg,
    float* __restrict__ og,
    const __fp16* __restrict__ bexp_blk)   // this block's [2][22][22][256] f16 tiles
{
    __shared__ u32 Kl[2][NPAD][4];       // f16 [2][352][8]
    __shared__ __fp16 Vt[2][8][360];     // dims x keys (padded stride)

    const int tid = threadIdx.x;
    const int pidx = blockIdx.x;
    const int grp = pidx % 3;
    const int rest = pidx / 3;
    const int h = rest & 1;
    const int wp = rest >> 1;            // 0..171
    const int w0 = 2 * wp;
    const int w1 = (w0 + 1 < NWTOK) ? w0 + 1 : NWTOK - 1;
    const int wh0 = w0 * 2 + h;
    const int wh1 = w1 * 2 + h;

    for (int i = tid; i < 2 * NPAD; i += 256) {
        const int sw = (i >= NPAD) ? 1 : 0;
        const int st = i - sw * NPAD;
        const size_t qpl = (size_t)(sw ? wh1 : wh0) * QPLANE;
        if (st < NWTOK) {
            *(uint4*)&Kl[sw][st][0] = ((const uint4*)(kg + qpl))[st];
            const uint4 vw = ((const uint4*)(vg + qpl))[st];
            const h2 v01 = __builtin_bit_cast(h2, vw.x);
            const h2 v23 = __builtin_bit_cast(h2, vw.y);
            const h2 v45 = __builtin_bit_cast(h2, vw.z);
            const h2 v67 = __builtin_bit_cast(h2, vw.w);
            Vt[sw][0][st] = v01.x; Vt[sw][1][st] = v01.y;
            Vt[sw][2][st] = v23.x; Vt[sw][3][st] = v23.y;
            Vt[sw][4][st] = v45.x; Vt[sw][5][st] = v45.y;
            Vt[sw][6][st] = v67.x; Vt[sw][7][st] = v67.y;
        } else {
            *(uint4*)&Kl[sw][st][0] = make_uint4(0, 0, 0, 0);
            #pragma unroll
            for (int d = 0; d < 8; ++d) Vt[sw][d][st] = (__fp16)0.f;
        }
    }
    __syncthreads();

    const int wv = tid >> 6;
    const int p = grp * 4 + wv;       // qt-pair index
    if (p >= 11) return;

    const int lane = tid & 63;
    const int n = lane & 15;
    const int g4 = (lane >> 4) * 4;
    const h4 zeroh = __builtin_bit_cast(h4, make_uint2(0u, 0u));

    const int qiA = (2 * p) * 16 + n;   // always < 343
    const int qiB = qiA + 16;           // may exceed 342 for p == 10
    h4 bqA0 = zeroh, bqB0 = zeroh, bqA1 = zeroh, bqB1 = zeroh;
    if (g4 < 8) {
        const size_t q0 = (size_t)wh0 * QPLANE;
        const size_t q1 = (size_t)wh1 * QPLANE;
        bqA0 = __builtin_bit_cast(h4, *(const uint2*)(qg + q0 + qiA * 4 + (g4 >> 1)));
        bqA1 = __builtin_bit_cast(h4, *(const uint2*)(qg + q1 + qiA * 4 + (g4 >> 1)));
        if (qiB < NWTOK) {
            bqB0 = __builtin_bit_cast(h4, *(const uint2*)(qg + q0 + qiB * 4 + (g4 >> 1)));
            bqB1 = __builtin_bit_cast(h4, *(const uint2*)(qg + q1 + qiB * 4 + (g4 >> 1)));
        }
    }

    const int laneoff = n * 16 + g4;
    const __fp16* trowA = bexp_blk + ((size_t)(h * 484) + (size_t)(2 * p) * NTILE) * 256 + laneoff;
    const __fp16* trowB = trowA + (size_t)NTILE * 256;

    f32x4 accA0 = {0.f, 0.f, 0.f, 0.f}, accB0 = {0.f, 0.f, 0.f, 0.f};
    f32x4 accA1 = {0.f, 0.f, 0.f, 0.f}, accB1 = {0.f, 0.f, 0.f, 0.f};
    float lA0 = 0.f, lB0 = 0.f, lA1 = 0.f, lB1 = 0.f;

    for (int kt = 0; kt < NTILE; ++kt) {
        const uint2 cbA16 = *(const uint2*)(trowA + kt * 256);
        const uint2 cbB16 = *(const uint2*)(trowB + kt * 256);
        const h2 alo = __builtin_bit_cast(h2, cbA16.x);
        const h2 ahi = __builtin_bit_cast(h2, cbA16.y);
        const h2 blo = __builtin_bit_cast(h2, cbB16.x);
        const h2 bhi = __builtin_bit_cast(h2, cbB16.y);
        f32x4 cbAf, cbBf;
        cbAf[0] = (float)alo.x; cbAf[1] = (float)alo.y;
        cbAf[2] = (float)ahi.x; cbAf[3] = (float)ahi.y;
        cbBf[0] = (float)blo.x; cbBf[1] = (float)blo.y;
        cbBf[2] = (float)bhi.x; cbBf[3] = (float)bhi.y;

        h4 ak0 = zeroh, ak1 = zeroh;
        if (g4 < 8) {
            ak0 = __builtin_bit_cast(h4, *(const uint2*)(&Kl[0][kt * 16 + n][g4 >> 1]));
            ak1 = __builtin_bit_cast(h4, *(const uint2*)(&Kl[1][kt * 16 + n][g4 >> 1]));
        }
        h4 av0 = zeroh, av1 = zeroh;
        if (n < 8) {
            av0 = *(const h4*)&Vt[0][n][kt * 16 + g4];
            av1 = *(const h4*)&Vt[1][n][kt * 16 + g4];
        }

        f32x4 sA0 = __builtin_amdgcn_mfma_f32_16x16x16f16(ak0, bqA0, cbAf, 0, 0, 0);
        f32x4 sB0 = __builtin_amdgcn_mfma_f32_16x16x16f16(ak0, bqB0, cbBf, 0, 0, 0);
        f32x4 sA1 = __builtin_amdgcn_mfma_f32_16x16x16f16(ak1, bqA1, cbAf, 0, 0, 0);
        f32x4 sB1 = __builtin_amdgcn_mfma_f32_16x16x16f16(ak1, bqB1, cbBf, 0, 0, 0);

        const float pA00 = fast_exp2(sA0[0]);
        const float pA01 = fast_exp2(sA0[1]);
        const float pA02 = fast_exp2(sA0[2]);
        const float pA03 = fast_exp2(sA0[3]);
        const float pB00 = fast_exp2(sB0[0]);
        const float pB01 = fast_exp2(sB0[1]);
        const float pB02 = fast_exp2(sB0[2]);
        const float pB03 = fast_exp2(sB0[3]);
        const float pA10 = fast_exp2(sA1[0]);
        const float pA11 = fast_exp2(sA1[1]);
        const float pA12 = fast_exp2(sA1[2]);
        const float pA13 = fast_exp2(sA1[3]);
        const float pB10 = fast_exp2(sB1[0]);
        const float pB11 = fast_exp2(sB1[1]);
        const float pB12 = fast_exp2(sB1[2]);
        const float pB13 = fast_exp2(sB1[3]);

        lA0 += (pA00 + pA01) + (pA02 + pA03);
        lB0 += (pB00 + pB01) + (pB02 + pB03);
        lA1 += (pA10 + pA11) + (pA12 + pA13);
        lB1 += (pB10 + pB11) + (pB12 + pB13);

        const h4 bpA0 = packh4(pA00, pA01, pA02, pA03);
        const h4 bpB0 = packh4(pB00, pB01, pB02, pB03);
        const h4 bpA1 = packh4(pA10, pA11, pA12, pA13);
        const h4 bpB1 = packh4(pB10, pB11, pB12, pB13);

        accA0 = __builtin_amdgcn_mfma_f32_16x16x16f16(av0, bpA0, accA0, 0, 0, 0);
        accB0 = __builtin_amdgcn_mfma_f32_16x16x16f16(av0, bpB0, accB0, 0, 0, 0);
        accA1 = __builtin_amdgcn_mfma_f32_16x16x16f16(av1, bpA1, accA1, 0, 0, 0);
        accB1 = __builtin_amdgcn_mfma_f32_16x16x16f16(av1, bpB1, accB1, 0, 0, 0);
    }

    lA0 += __shfl_xor(lA0, 16); lA0 += __shfl_xor(lA0, 32);
    lB0 += __shfl_xor(lB0, 16); lB0 += __shfl_xor(lB0, 32);
    lA1 += __shfl_xor(lA1, 16); lA1 += __shfl_xor(lA1, 32);
    lB1 += __shfl_xor(lB1, 16); lB1 += __shfl_xor(lB1, 32);

    if (g4 < 8) {
        {
            const f32x4 o0 = accA0 * (1.f / lA0);
            *(f32x4*)(og + (size_t)wh0 * OPLANE + qiA * 8 + g4) = o0;
            const f32x4 o1 = accA1 * (1.f / lA1);
            *(f32x4*)(og + (size_t)wh1 * OPLANE + qiA * 8 + g4) = o1;
        }
        if (qiB < NWTOK) {
            const f32x4 o0 = accB0 * (1.f / lB0);
            *(f32x4*)(og + (size_t)wh0 * OPLANE + qiB * 8 + g4) = o0;
            const f32x4 o1 = accB1 * (1.f / lB1);
            *(f32x4*)(og + (size_t)wh1 * OPLANE + qiB * 8 + g4) = o1;
        }
    }
}

// ------- K_post (MFMA): wave = one (window, qt) tile of 16 tokens -------
__global__ __launch_bounds__(256, 4) void k_post(
    float* __restrict__ xe,
    const float* __restrict__ og,
    u32* __restrict__ qg,
    u32* __restrict__ kg,
    u32* __restrict__ vg,
    const float* __restrict__ proj_w,
    const float* __restrict__ proj_b,
    const float* __restrict__ n2_g,
    const float* __restrict__ n2_b,
    const float* __restrict__ fc1_w,
    const float* __restrict__ fc1_b,
    const float* __restrict__ fc2_w,
    const float* __restrict__ fc2_b,
    const float* __restrict__ n1_g_nx,
    const float* __restrict__ n1_b_nx,
    const float* __restrict__ qkv_w_nx,
    float* __restrict__ outp,
    const int last)
{
    __shared__ u32 projh[128];     // (16,16) f16: row*8 + k/2
    __shared__ u32 fc1h[512];      // (64,16) f16
    __shared__ u32 fc2h[512];      // (16,64) f16: row*32 + k/2
    __shared__ u32 qkvh[384];      // (48,16) f16
    __shared__ float projb_s[16], n2g_s[16], n2b_s[16], fc2b_s[16], n1g_s[16], n1b_s[16];
    __shared__ float fc1b_s[64];
    const int tid = threadIdx.x;
    if (tid < 128) {
        const float2 p = ((const float2*)proj_w)[tid];
        projh[tid] = packh2(p.x, p.y);
    }
    for (int i = tid; i < 512; i += 256) {
        const float2 a = ((const float2*)fc1_w)[i];
        fc1h[i] = packh2(a.x, a.y);
        const float2 b = ((const float2*)fc2_w)[i];
        fc2h[i] = packh2(b.x, b.y);
    }
    for (int i = tid; i < 384; i += 256) {
        const float2 a = ((const float2*)qkv_w_nx)[i];
        qkvh[i] = packh2(a.x, a.y);
    }
    if (tid < 16) {
        projb_s[tid] = proj_b[tid];
        n2g_s[tid] = n2_g[tid]; n2b_s[tid] = n2_b[tid];
        fc2b_s[tid] = fc2_b[tid];
        n1g_s[tid] = n1_g_nx[tid]; n1b_s[tid] = n1_b_nx[tid];
    }
    if (tid < 64) fc1b_s[tid] = fc1_b[tid];
    __syncthreads();

    const int wave_id = blockIdx.x * 4 + (tid >> 6);
    if (wave_id >= NWTOK * NTILE) return;   // 7546 tiles
    const int w = wave_id / NTILE;
    const int qt = wave_id - w * NTILE;

    const int lane = tid & 63;
    const int tcol = lane & 15;             // token column (also A row index)
    const int g4 = (lane >> 4) * 4;         // channel group base
    const int tok = qt * 16 + tcol;
    const bool valid = (tok < NWTOK);
    const int tokc = valid ? tok : (NWTOK - 1);

    const f32x4 zero = {0.f, 0.f, 0.f, 0.f};

    // ---- B-frag: o^T (ch g4..g4+3 of this token) ----
    const int pl = g4 >> 3;                 // head plane
    const int po = g4 & 7;                  // within-plane ch offset (0 or 4)
    const float4 o4 = *(const float4*)(og + (size_t)(w * 2 + pl) * OPLANE + tokc * 8 + po);
    const h4 oB = packh4(o4.x, o4.y, o4.z, o4.w);

    // ---- proj + residual + bias ----
    const uint2 apw = *(const uint2*)(projh + tcol * 8 + (g4 >> 1));
    const f32x4 d1 = __builtin_amdgcn_mfma_f32_16x16x16f16(
        __builtin_bit_cast(h4, apw), oB, zero, 0, 0, 0);
    const float4 xe4 = *(const float4*)(xe + (size_t)(w * NWTOK + tokc) * 16 + g4);
    const float4 pb4 = *(const float4*)(projb_s + g4);
    float xr0 = d1[0] + xe4.x + pb4.x;
    float xr1 = d1[1] + xe4.y + pb4.y;
    float xr2 = d1[2] + xe4.z + pb4.z;
    float xr3 = d1[3] + xe4.w + pb4.w;

    // ---- LN2 (cross-lane over channel groups) ----
    float s = (xr0 + xr1) + (xr2 + xr3);
    s += __shfl_xor(s, 16); s += __shfl_xor(s, 32);
    float mu = s * 0.0625f;
    float v0 = xr0 - mu, v1 = xr1 - mu, v2 = xr2 - mu, v3 = xr3 - mu;
    float vv = fmaf(v0, v0, fmaf(v1, v1, fmaf(v2, v2, v3 * v3)));
    vv += __shfl_xor(vv, 16); vv += __shfl_xor(vv, 32);
    float rs = rsqrtf(vv * 0.0625f + 1e-5f);
    const float4 g2 = *(const float4*)(n2g_s + g4);
    const float4 b2 = *(const float4*)(n2b_s + g4);
    const h4 zB = packh4(v0 * rs * g2.x + b2.x, v1 * rs * g2.y + b2.y,
                         v2 * rs * g2.z + b2.z, v3 * rs * g2.w + b2.w);

    // ---- fc1 (4 MFMAs) + bias + GELU -> 4 B-frags ----
    h4 hB[4];
    #pragma unroll
    for (int i = 0; i < 4; ++i) {
        const uint2 aw = *(const uint2*)(fc1h + (i * 16 + tcol) * 8 + (g4 >> 1));
        f32x4 hd = __builtin_amdgcn_mfma_f32_16x16x16f16(
            __builtin_bit_cast(h4, aw), zB, zero, 0, 0, 0);
        const float4 fb = *(const float4*)(fc1b_s + i * 16 + g4);
        hB[i] = packh4(gelu_exact(hd[0] + fb.x), gelu_exact(hd[1] + fb.y),
                       gelu_exact(hd[2] + fb.z), gelu_exact(hd[3] + fb.w));
    }

    // ---- fc2 (K=64: 4 chained MFMAs) + bias + residual ----
    f32x4 acc = zero;
    #pragma unroll
    for (int j = 0; j < 4; ++j) {
        const uint2 aw = *(const uint2*)(fc2h + tcol * 32 + ((j * 16 + g4) >> 1));
        acc = __builtin_amdgcn_mfma_f32_16x16x16f16(
            __builtin_bit_cast(h4, aw), hB[j], acc, 0, 0, 0);
    }
    const float4 f2b = *(const float4*)(fc2b_s + g4);
    xr0 += acc[0] + f2b.x;
    xr1 += acc[1] + f2b.y;
    xr2 += acc[2] + f2b.z;
    xr3 += acc[3] + f2b.w;

    if (last) {
        if (valid) {
            const int wd = w / 49, wr2 = w - wd * 49, whh = wr2 / 7, www = wr2 - whh * 7;
            const int tz = tok / 49, tr2 = tok - tz * 49, ty = tr2 / 7, tx = tr2 - ty * 7;
            const int g = ((wd * 7 + tz) * 49 + (whh * 7 + ty)) * 49 + (www * 7 + tx);
            outp[(size_t)(g4 + 0) * NTOK + g] = xr0;
            outp[(size_t)(g4 + 1) * NTOK + g] = xr1;
            outp[(size_t)(g4 + 2) * NTOK + g] = xr2;
            outp[(size_t)(g4 + 3) * NTOK + g] = xr3;
        }
        return;
    }

    if (valid) {
        float4 st = make_float4(xr0, xr1, xr2, xr3);
        *(float4*)(xe + (size_t)(w * NWTOK + tok) * 16 + g4) = st;
    }

    // ---- LN1 ----
    s = (xr0 + xr1) + (xr2 + xr3);
    s += __shfl_xor(s, 16); s += __shfl_xor(s, 32);
    mu = s * 0.0625f;
    v0 = xr0 - mu; v1 = xr1 - mu; v2 = xr2 - mu; v3 = xr3 - mu;
    vv = fmaf(v0, v0, fmaf(v1, v1, fmaf(v2, v2, v3 * v3)));
    vv += __shfl_xor(vv, 16); vv += __shfl_xor(vv, 32);
    rs = rsqrtf(vv * 0.0625f + 1e-5f);
    const float4 g1 = *(const float4*)(n1g_s + g4);
    const float4 b1 = *(const float4*)(n1b_s + g4);
    const h4 yB = packh4(v0 * rs * g1.x + b1.x, v1 * rs * g1.y + b1.y,
                         v2 * rs * g1.z + b1.z, v3 * rs * g1.w + b1.w);

    // ---- QKV for next block (3 MFMAs), store f16 rows ----
    const int head = g4 >> 3;
    const int uoff = (g4 & 7) >> 1;         // u32 offset within the token's 4-u32 row
    const size_t qpl = (size_t)(w * 2 + head) * QPLANE + tok * 4 + uoff;
    #pragma unroll
    for (int m = 0; m < 3; ++m) {
        const uint2 aw = *(const uint2*)(qkvh + (m * 16 + tcol) * 8 + (g4 >> 1));
        f32x4 d = __builtin_amdgcn_mfma_f32_16x16x16f16(
            __builtin_bit_cast(h4, aw), yB, zero, 0, 0, 0);
        float sc = (m == 0) ? QSCALE : 1.f;
        const u32 lo = packh2(d[0] * sc, d[1] * sc);
        const u32 hi = packh2(d[2] * sc, d[3] * sc);
        if (valid) {
            u32* dst = (m == 0 ? qg : (m == 1 ? kg : vg)) + qpl;
            dst[0] = lo;
            dst[1] = hi;
        }
    }
}

extern "C" void kernel_launch(void* const* d_in, const int* in_sizes, int n_in,
                              void* d_out, int out_size, void* d_ws, size_t ws_size,
                              hipStream_t stream) {
    const float* x       = (const float*)d_in[0];
    const float* pe_w    = (const float*)d_in[1];
    const float* pe_bias = (const float*)d_in[2];
    const float* pe_g    = (const float*)d_in[3];
    const float* pe_b    = (const float*)d_in[4];
    const float* n1_g    = (const float*)d_in[5];
    const float* n1_b    = (const float*)d_in[6];
    const float* qkv_w   = (const float*)d_in[7];
    const float* rpb     = (const float*)d_in[8];
    const float* proj_w  = (const float*)d_in[9];
    const float* proj_b  = (const float*)d_in[10];
    const float* n2_g    = (const float*)d_in[11];
    const float* n2_b    = (const float*)d_in[12];
    const float* fc1_w   = (const float*)d_in[13];
    const float* fc1_b   = (const float*)d_in[14];
    const float* fc2_w   = (const float*)d_in[15];
    const float* fc2_b   = (const float*)d_in[16];

    float* ws = (float*)d_ws;
    const size_t SEG = (size_t)NTOK * 16;     // 1,882,384 floats
    const size_t QSEG = (size_t)686 * QPLANE; // 941,192 u32
    float* xe = ws;
    u32* qg = (u32*)(ws + SEG);
    u32* kg = qg + QSEG;
    u32* vg = kg + QSEG;
    float* og = (float*)(vg + QSEG);                  // 686*2744 f32
    __fp16* bexp16 = (__fp16*)(og + (size_t)686 * OPLANE); // 6*484*256 f16
    float* out = (float*)d_out;

    const int k0_grid = NBIAS_BLK + (NK0_TILE + 3) / 4;   // bias tiles + k0 tiles
    k0_fused<<<k0_grid, 256, 0, stream>>>(
        x, pe_w, pe_bias, pe_g, pe_b, n1_g, n1_b, qkv_w, rpb,
        xe, qg, kg, vg, bexp16);

    const int attn_grid = 172 * 2 * 3;                // (window-pair, head, qt-group)
    const int post_grid = (NWTOK * NTILE + 3) / 4;    // 7546 tiles, 4 waves/WG
    for (int i = 0; i < 3; ++i) {
        const int last = (i == 2) ? 1 : 0;
        const int nx = last ? i : i + 1;
        k_attn<<<attn_grid, 256, 0, stream>>>(
            qg, kg, vg, og, bexp16 + (size_t)i * 2 * 484 * 256);
        k_post<<<post_grid, 256, 0, stream>>>(
            xe, og, qg, kg, vg,
            proj_w + (size_t)i * 256, proj_b + (size_t)i * 16,
            n2_g + (size_t)i * 16, n2_b + (size_t)i * 16,
            fc1_w + (size_t)i * 1024, fc1_b + (size_t)i * 64,
            fc2_w + (size_t)i * 1024, fc2_b + (size_t)i * 16,
            n1_g + (size_t)nx * 16, n1_b + (size_t)nx * 16,
            qkv_w + (size_t)nx * 768,
            out, last);
    }
}